// Round 9
// baseline (143.382 us; speedup 1.0000x reference)
//
#include <hip/hip_runtime.h>
#include <math.h>

#define NB 2
#define NO 512
#define NQ 512
#define OUT_DIM 128
#define LPAD 516   // logits row pitch (floats): 16B-mult, bank-staggered

typedef __attribute__((ext_vector_type(8))) _Float16 half8;  // 4 VGPR
typedef __attribute__((ext_vector_type(4))) _Float16 half4;  // 2 VGPR
typedef __attribute__((ext_vector_type(4))) float f32x4;     // MFMA acc

__device__ __forceinline__ float softplus_f(float x) {
  return x > 0.0f ? x + log1pf(expf(-x)) : log1pf(expf(x));
}
__device__ __forceinline__ half8 splat8(_Float16 v) {
  return (half8){v, v, v, v, v, v, v, v};
}
__device__ __forceinline__ half8 fma8(half8 a, half8 b, half8 c) {
  return __builtin_elementwise_fma(a, b, c);
}
__device__ __forceinline__ half8 max8(half8 a, half8 b) {
  return __builtin_elementwise_max(a, b);
}
// async global->LDS, 16B per lane; dest = lds_base + lane*16 (wave-uniform base)
__device__ __forceinline__ void gll16(const void* g, void* l) {
  __builtin_amdgcn_global_load_lds(
      (const __attribute__((address_space(1))) unsigned int*)g,
      (__attribute__((address_space(3))) unsigned int*)l, 16, 0, 0);
}

// ---------------------------------------------------------------------------
// Prep: fused 2-layer MLP -> VT (f16, head-transposed [b][h][d][o]).
__global__ __launch_bounds__(1024) void prep_kernel(
    const float* __restrict__ h_obs, const float* __restrict__ fw1,
    const float* __restrict__ fb1, const float* __restrict__ fw2,
    const float* __restrict__ fb2, _Float16* __restrict__ VT)
{
  __shared__ float s_red[4][4][256];
  __shared__ float s_hid[4][256];
  const int n  = threadIdx.x & 255;
  const int ks = threadIdx.x >> 8;
  const int r0 = blockIdx.x * 4;
  const int k0 = ks * 64;
  float a0 = 0.f, a1 = 0.f, a2 = 0.f, a3 = 0.f;
  #pragma unroll 8
  for (int kk = 0; kk < 64; ++kk) {
    int k = k0 + kk;
    float w = fw1[k * 256 + n];
    a0 = fmaf(h_obs[(r0 + 0) * 256 + k], w, a0);
    a1 = fmaf(h_obs[(r0 + 1) * 256 + k], w, a1);
    a2 = fmaf(h_obs[(r0 + 2) * 256 + k], w, a2);
    a3 = fmaf(h_obs[(r0 + 3) * 256 + k], w, a3);
  }
  s_red[ks][0][n] = a0; s_red[ks][1][n] = a1;
  s_red[ks][2][n] = a2; s_red[ks][3][n] = a3;
  __syncthreads();
  if (ks == 0) {
    float bb = fb1[n];
    #pragma unroll
    for (int r = 0; r < 4; ++r) {
      float v = s_red[0][r][n] + s_red[1][r][n] + s_red[2][r][n] + s_red[3][r][n] + bb;
      s_hid[r][n] = fmaxf(v, 0.f);
    }
  }
  __syncthreads();
  float c0 = 0.f, c1 = 0.f, c2 = 0.f, c3 = 0.f;
  #pragma unroll 8
  for (int kk = 0; kk < 64; ++kk) {
    int k = k0 + kk;
    float w = fw2[k * 256 + n];
    c0 = fmaf(s_hid[0][k], w, c0);
    c1 = fmaf(s_hid[1][k], w, c1);
    c2 = fmaf(s_hid[2][k], w, c2);
    c3 = fmaf(s_hid[3][k], w, c3);
  }
  __syncthreads();
  s_red[ks][0][n] = c0; s_red[ks][1][n] = c1;
  s_red[ks][2][n] = c2; s_red[ks][3][n] = c3;
  __syncthreads();
  if (ks == 0) {
    float bb = fb2[n];
    float vr[4];
    #pragma unroll
    for (int r = 0; r < 4; ++r)
      vr[r] = s_red[0][r][n] + s_red[1][r][n] + s_red[2][r][n] + s_red[3][r][n] + bb;
    // transpose store: thread n owns column (h,d); 4 consecutive o
    const int h  = n >> 5, d = n & 31;
    const int bb_ = r0 >> 9, o0 = r0 & 511;
    half4 pv;
    #pragma unroll
    for (int r = 0; r < 4; ++r) pv[r] = (_Float16)vr[r];
    *(half4*)(VT + ((size_t)((bb_ * 8 + h) * 32 + d)) * 512 + o0) = pv;
  }
}

// ---------------------------------------------------------------------------
// Fused attention (r4 champion structure). QT=2 per block, 512 threads.
// Phase 1: f16 MFMA delta; ao built in-register (rank-3 pos projection).
// Phase 2+3: per-wave (=head), barrier-free; VT staged via global_load_lds
//   into wave-private dead LDS (4-buffer rotation, counted vmcnt).
// out_proj REMOVED: epilogue writes the tiny HV intermediate to global;
//   a separate proj kernel does out_proj with 16x W reuse (cuts W L2
//   traffic 256 MB -> 32 MB and drops attn's per-block W stream).
__global__ __launch_bounds__(512, 4) void attn_fused(
    const _Float16* __restrict__ VT,     // [b][h][d][o] f16
    const float* __restrict__ kw1,       // (9, 256)
    const float* __restrict__ kb1,       // (256)
    const float* __restrict__ kw2,       // (256, 8)
    const float* __restrict__ kb2,       // (8)
    const float* __restrict__ log_sigma, // (8)
    const float* __restrict__ pos_obs,   // (B*NO, 3)
    const float* __restrict__ pos_query, // (B*NQ, 3)
    float* __restrict__ HVg)             // [B*NQ][2][256] f32
{
  __shared__ __align__(16) float s_logits[2][8 * LPAD];   // 33024 B; ph3: per-wave VT stage
  __shared__ __align__(16) _Float16 s_P16[2][8][520];     // 16640 B (P, f16)
  __shared__ half8 s_Bh[512];                             // 8192 B (kw2 frags; ph3: buf0)
  __shared__ __align__(16) float s_pool[256];             // 1024 B (aq f16)
  __shared__ __align__(16) float s_po[3][516];            // 6192 B (pos_obs, SoA)
  __shared__ __align__(16) _Float16 s_co[3][264];         // 1584 B (ao coeff table)

  _Float16* s_aq2 = (_Float16*)s_pool;   // [2][256] f16 (phase 1 only)

  const int t   = threadIdx.x;
  const int bq0 = blockIdx.x * 2;
  const int b   = bq0 >> 9;

  // ---- prologue -----------------------------------------------------------
  float pqx[2], pqy[2], pqz[2];
  #pragma unroll
  for (int q = 0; q < 2; ++q) {
    pqx[q] = pos_query[(bq0 + q) * 3 + 0];
    pqy[q] = pos_query[(bq0 + q) * 3 + 1];
    pqz[q] = pos_query[(bq0 + q) * 3 + 2];
  }
  // aq[q][j] in f16
  {
    const int q = t >> 8, j = t & 255;
    float c0 = kw1[0 * 256 + j] + kw1[6 * 256 + j];
    float c1 = kw1[1 * 256 + j] + kw1[7 * 256 + j];
    float c2 = kw1[2 * 256 + j] + kw1[8 * 256 + j];
    s_aq2[q * 256 + j] = (_Float16)
        fmaf(pqx[q], c0, fmaf(pqy[q], c1, fmaf(pqz[q], c2, kb1[j])));
  }
  // ao coefficient table (rank-3): co[c][j], f16
  if (t < 256) {
    const int j = t;
    s_co[0][j] = (_Float16)(kw1[3 * 256 + j] - kw1[6 * 256 + j]);
    s_co[1][j] = (_Float16)(kw1[4 * 256 + j] - kw1[7 * 256 + j]);
    s_co[2][j] = (_Float16)(kw1[5 * 256 + j] - kw1[8 * 256 + j]);
  }
  // pos_obs SoA + logits prefill (rbf + kb2) for o = t, both q, all h.
  // log(exp(x)+1e-8) ~= max(x, log(1e-8)); clamp region weight < e^-15.
  {
    const int o = t;
    const float* p = pos_obs + (size_t)(b * NO + o) * 3;
    float px = p[0], py = p[1], pz = p[2];
    s_po[0][o] = px; s_po[1][o] = py; s_po[2][o] = pz;
    float d2q[2];
    #pragma unroll
    for (int q = 0; q < 2; ++q) {
      float r0 = pqx[q] - px, r1 = pqy[q] - py, r2 = pqz[q] - pz;
      d2q[q] = r0 * r0 + r1 * r1 + r2 * r2;
    }
    #pragma unroll
    for (int h = 0; h < 8; ++h) {
      float sg  = __expf(log_sigma[h]);
      float inv = 1.0f / (sg * sg + 1e-6f);
      float kbv = kb2[h];
      s_logits[0][h * LPAD + o] = fmaxf(-d2q[0] * inv, -18.420681f) + kbv;
      s_logits[1][h * LPAD + o] = fmaxf(-d2q[1] * inv, -18.420681f) + kbv;
    }
  }
  // B fragments: kw2 as f16
  {
    const int kstep = t >> 6, lane = t & 63;
    const int nh = lane & 15;
    const int kb_ = kstep * 32 + ((lane >> 4) & 3) * 8;
    half8 b8;
    #pragma unroll
    for (int i = 0; i < 8; ++i) {
      float v = (nh < 8) ? kw2[(kb_ + i) * 8 + nh] : 0.f;
      b8[i] = (_Float16)v;
    }
    s_Bh[kstep * 64 + lane] = b8;
  }
  __syncthreads();

  // ---- phase 1: f16 MFMA delta; A = relu(aq + pos.co) all in packed f16 ---
  {
    const int wave = t >> 6, lane = t & 63;
    const int quad = lane >> 4, mrow = lane & 15;
    const int tb   = wave * 4;
    _Float16 pxh[4], pyh[4], pzh[4];
    #pragma unroll
    for (int jt = 0; jt < 4; ++jt) {
      const int o = (tb + jt) * 16 + mrow;
      pxh[jt] = (_Float16)s_po[0][o];
      pyh[jt] = (_Float16)s_po[1][o];
      pzh[jt] = (_Float16)s_po[2][o];
    }
    f32x4 C[2][4];
    #pragma unroll
    for (int q = 0; q < 2; ++q)
      #pragma unroll
      for (int jt = 0; jt < 4; ++jt) C[q][jt] = (f32x4){0.f, 0.f, 0.f, 0.f};

    const half8 z8 = {0, 0, 0, 0, 0, 0, 0, 0};
    #pragma unroll
    for (int kstep = 0; kstep < 8; ++kstep) {
      const int koff = kstep * 32 + quad * 8;
      half8 c0 = *(const half8*)&s_co[0][koff];
      half8 c1 = *(const half8*)&s_co[1][koff];
      half8 c2 = *(const half8*)&s_co[2][koff];
      half8 aq0 = *(const half8*)(s_aq2 + koff);
      half8 aq1 = *(const half8*)(s_aq2 + 256 + koff);
      half8 bh  = s_Bh[kstep * 64 + lane];
      #pragma unroll
      for (int jt = 0; jt < 4; ++jt) {
        half8 ao = fma8(splat8(pxh[jt]), c0,
                   fma8(splat8(pyh[jt]), c1, splat8(pzh[jt]) * c2));
        half8 a0 = max8(aq0 + ao, z8);
        half8 a1 = max8(aq1 + ao, z8);
        C[0][jt] = __builtin_amdgcn_mfma_f32_16x16x32_f16(a0, bh, C[0][jt], 0, 0, 0);
        C[1][jt] = __builtin_amdgcn_mfma_f32_16x16x32_f16(a1, bh, C[1][jt], 0, 0, 0);
      }
    }
    // epilogue: D[n=h=lane&15][m=quad*4+r]; add delta into prefilled logits
    const int hh = lane & 15;
    if (hh < 8) {
      #pragma unroll
      for (int q = 0; q < 2; ++q)
        #pragma unroll
        for (int jt = 0; jt < 4; ++jt) {
          const int ob2 = (tb + jt) * 16 + quad * 4;
          #pragma unroll
          for (int r = 0; r < 4; ++r)
            s_logits[q][hh * LPAD + ob2 + r] += C[q][jt][r];
        }
    }
  }
  __syncthreads();   // logits complete; waves fully independent from here on

  // ---- phase 2+3: per-wave (=head), barrier-free --------------------------
  {
    const int h = t >> 6, lane = t & 63;
    const int kg = lane >> 4, dl = lane & 15;
    // wave-private staging buffers (all dead for everyone else):
    //   buf0 = own s_Bh slot; buf1/buf3 = own q0 logits row; buf2 = own q1 row
    char* stg0 = (char*)s_Bh + h * 1024;
    char* b1   = (char*)&s_logits[0][h * LPAD];
    char* b3   = b1 + 1024;
    char* b2   = (char*)&s_logits[1][h * LPAD];
    const _Float16* vsrc = VT + ((size_t)(b * 8 + h) << 14)
                         + (lane >> 1) * 512 + (lane & 1) * 8;
    gll16(vsrc, stg0);                 // slice 0: hides under softmax

    // softmax, q0/q1 interleaved (2 independent shfl chains -> ILP)
    float invq0, invq1;
    {
      const float* pl0 = &s_logits[0][h * LPAD];
      const float* pl1 = &s_logits[1][h * LPAD];
      float l0[8], l1[8];
      float m0 = -1e30f, m1 = -1e30f;
      #pragma unroll
      for (int k = 0; k < 8; ++k) {
        l0[k] = pl0[k * 64 + lane];
        l1[k] = pl1[k * 64 + lane];
        m0 = fmaxf(m0, l0[k]);
        m1 = fmaxf(m1, l1[k]);
      }
      #pragma unroll
      for (int off = 32; off >= 1; off >>= 1) {
        m0 = fmaxf(m0, __shfl_xor(m0, off, 64));
        m1 = fmaxf(m1, __shfl_xor(m1, off, 64));
      }
      float s0 = 0.f, s1 = 0.f;
      _Float16* pp0 = &s_P16[0][h][0];
      _Float16* pp1 = &s_P16[1][h][0];
      #pragma unroll
      for (int k = 0; k < 8; ++k) {
        float p0 = __expf(l0[k] - m0);
        float p1 = __expf(l1[k] - m1);
        s0 += p0; s1 += p1;
        pp0[k * 64 + lane] = (_Float16)p0;
        pp1[k * 64 + lane] = (_Float16)p1;
      }
      #pragma unroll
      for (int off = 32; off >= 1; off >>= 1) {
        s0 += __shfl_xor(s0, off, 64);
        s1 += __shfl_xor(s1, off, 64);
      }
      invq0 = 1.0f / s0; invq1 = 1.0f / s1;
    }
    // own logits rows now fully read -> become staging buffers
    gll16(vsrc + 16, b1);              // slice 1
    gll16(vsrc + 32, b2);              // slice 2
    gll16(vsrc + 48, b3);              // slice 3

    const char* pE = ((kg & 2) ? b1 : stg0) + dl * 32 + (kg & 1) * 16;
    const char* pO = ((kg & 2) ? b3 : b2)   + dl * 32 + (kg & 1) * 16;
    const _Float16* pB = &s_P16[lane & 1][h][0];
    f32x4 Cm0 = {0.f, 0.f, 0.f, 0.f}, Cm1 = Cm0, Cv0 = Cm0, Cv1 = Cm0;
    #pragma unroll
    for (int kp = 0; kp < 8; ++kp) {
      // even K-step: slices 4kp, 4kp+1 (buf0/buf1)
      asm volatile("s_waitcnt vmcnt(2)" ::: "memory");
      {
        half8 am0 = *(const half8*)(pE);
        half8 am1 = *(const half8*)(pE + 512);       // d + 16
        half8 pb  = *(const half8*)(pB + (2 * kp) * 32 + kg * 8);
        half8 av0 = am0 * am0;
        half8 av1 = am1 * am1;
        __builtin_amdgcn_s_setprio(1);
        Cm0 = __builtin_amdgcn_mfma_f32_16x16x32_f16(am0, pb, Cm0, 0, 0, 0);
        Cm1 = __builtin_amdgcn_mfma_f32_16x16x32_f16(am1, pb, Cm1, 0, 0, 0);
        Cv0 = __builtin_amdgcn_mfma_f32_16x16x32_f16(av0, pb, Cv0, 0, 0, 0);
        Cv1 = __builtin_amdgcn_mfma_f32_16x16x32_f16(av1, pb, Cv1, 0, 0, 0);
        __builtin_amdgcn_s_setprio(0);
      }
      if (kp < 7) {
        asm volatile("s_waitcnt lgkmcnt(0)" ::: "memory");  // reads done; safe to overwrite
        gll16(vsrc + (4 * kp + 4) * 16, stg0);
        gll16(vsrc + (4 * kp + 5) * 16, b1);
      }
      // odd K-step: slices 4kp+2, 4kp+3 (buf2/buf3)
      if (kp < 7) asm volatile("s_waitcnt vmcnt(2)" ::: "memory");
      else        asm volatile("s_waitcnt vmcnt(0)" ::: "memory");
      {
        half8 am0 = *(const half8*)(pO);
        half8 am1 = *(const half8*)(pO + 512);
        half8 pb  = *(const half8*)(pB + (2 * kp + 1) * 32 + kg * 8);
        half8 av0 = am0 * am0;
        half8 av1 = am1 * am1;
        __builtin_amdgcn_s_setprio(1);
        Cm0 = __builtin_amdgcn_mfma_f32_16x16x32_f16(am0, pb, Cm0, 0, 0, 0);
        Cm1 = __builtin_amdgcn_mfma_f32_16x16x32_f16(am1, pb, Cm1, 0, 0, 0);
        Cv0 = __builtin_amdgcn_mfma_f32_16x16x32_f16(av0, pb, Cv0, 0, 0, 0);
        Cv1 = __builtin_amdgcn_mfma_f32_16x16x32_f16(av1, pb, Cv1, 0, 0, 0);
        __builtin_amdgcn_s_setprio(0);
      }
      if (kp < 7) {
        asm volatile("s_waitcnt lgkmcnt(0)" ::: "memory");
        gll16(vsrc + (4 * kp + 6) * 16, b2);
        gll16(vsrc + (4 * kp + 7) * 16, b3);
      }
    }
    // epilogue: C row = kg*4+r (=d_local), col = nq (=q). Normalize + var,
    // write HV intermediate straight to global (no phase 4 in this kernel).
    const int nq = lane & 15;
    if (nq < 2) {
      const float iv = nq ? invq1 : invq0;
      const int dbase = h * 32 + kg * 4;
      f32x4 m0, v0, m1, v1;
      #pragma unroll
      for (int r = 0; r < 4; ++r) {
        float a = Cm0[r] * iv;
        m0[r] = a; v0[r] = fmaxf(Cv0[r] * iv - a * a, 0.f);
        float c = Cm1[r] * iv;
        m1[r] = c; v1[r] = fmaxf(Cv1[r] * iv - c * c, 0.f);
      }
      float* hvq = HVg + (size_t)(bq0 + nq) * 2 * 256;
      *(f32x4*)(hvq + 0 * 256 + dbase)      = m0;   // kind 0: mean path
      *(f32x4*)(hvq + 1 * 256 + dbase)      = v0;   // kind 1: var path
      *(f32x4*)(hvq + 0 * 256 + dbase + 16) = m1;
      *(f32x4*)(hvq + 1 * 256 + dbase + 16) = v1;
    }
  }
}

// ---------------------------------------------------------------------------
// out_proj: out[mode][q][n] = (HV[q][mode] @ W_mode + bias_mode), softplus on
// var path. 8 q per block -> W read once per 8 queries (16x less W traffic
// than the fused phase-4). X loads are wave-uniform -> scalar-cache served.
__global__ __launch_bounds__(256) void proj_kernel(
    const float* __restrict__ HV,   // [B*NQ][2][256]
    const float* __restrict__ ow, const float* __restrict__ obias,
    const float* __restrict__ vw, const float* __restrict__ vbias,
    float* __restrict__ out)
{
  const int t = threadIdx.x;
  const int mode = t >> 7, n = t & 127;
  const int q0 = blockIdx.x * 8;
  const float* W = mode ? vw : ow;
  float acc[8] = {0.f, 0.f, 0.f, 0.f, 0.f, 0.f, 0.f, 0.f};
  for (int k = 0; k < 256; k += 4) {
    float w0 = W[(k + 0) * 128 + n];
    float w1 = W[(k + 1) * 128 + n];
    float w2 = W[(k + 2) * 128 + n];
    float w3 = W[(k + 3) * 128 + n];
    #pragma unroll
    for (int qq = 0; qq < 8; ++qq) {
      float4 x = *(const float4*)&HV[((size_t)(q0 + qq) * 2 + mode) * 256 + k];
      acc[qq] = fmaf(x.w, w3, fmaf(x.z, w2, fmaf(x.y, w1, fmaf(x.x, w0, acc[qq]))));
    }
  }
  const float bias = mode ? vbias[n] : obias[n];
  #pragma unroll
  for (int qq = 0; qq < 8; ++qq) {
    float v = acc[qq] + bias;
    if (mode) v = softplus_f(v);
    out[(size_t)mode * (NB * NQ * OUT_DIM) + (size_t)(q0 + qq) * OUT_DIM + n] = v;
  }
}

// ---------------------------------------------------------------------------
extern "C" void kernel_launch(void* const* d_in, const int* in_sizes, int n_in,
                              void* d_out, int out_size, void* d_ws, size_t ws_size,
                              hipStream_t stream)
{
  const float* h_obs     = (const float*)d_in[0];
  const float* pos_obs   = (const float*)d_in[1];
  const float* pos_query = (const float*)d_in[2];
  const float* fw1       = (const float*)d_in[3];
  const float* fb1       = (const float*)d_in[4];
  const float* fw2       = (const float*)d_in[5];
  const float* fb2       = (const float*)d_in[6];
  const float* log_sigma = (const float*)d_in[7];
  const float* kw1       = (const float*)d_in[8];
  const float* kb1       = (const float*)d_in[9];
  const float* kw2       = (const float*)d_in[10];
  const float* kb2       = (const float*)d_in[11];
  const float* ow        = (const float*)d_in[12];
  const float* ob        = (const float*)d_in[13];
  const float* vw        = (const float*)d_in[14];
  const float* vb        = (const float*)d_in[15];

  float* out = (float*)d_out;
  _Float16* ws = (_Float16*)d_ws;
  _Float16* VT = ws;                       // 262144 f16 = 512 KB
  float*    HV = (float*)(ws + 262144);    // 1024*2*256 f32 = 2 MB

  prep_kernel<<<256, 1024, 0, stream>>>(h_obs, fw1, fb1, fw2, fb2, VT);
  attn_fused<<<NB * NQ / 2, 512, 0, stream>>>(VT, kw1, kb1, kw2, kb2,
                                              log_sigma, pos_obs, pos_query, HV);
  proj_kernel<<<NB * NQ / 8, 256, 0, stream>>>(HV, ow, ob, vw, vb, out);
}

// Round 10
// 134.643 us; speedup vs baseline: 1.0649x; 1.0649x over previous
//
#include <hip/hip_runtime.h>
#include <math.h>

#define NB 2
#define NO 512
#define NQ 512
#define OUT_DIM 128
#define LPAD 516   // logits row pitch (floats): 16B-mult, bank-staggered

typedef __attribute__((ext_vector_type(8))) _Float16 half8;  // 4 VGPR
typedef __attribute__((ext_vector_type(4))) _Float16 half4;  // 2 VGPR
typedef __attribute__((ext_vector_type(4))) float f32x4;     // MFMA acc

__device__ __forceinline__ float softplus_f(float x) {
  return x > 0.0f ? x + log1pf(expf(-x)) : log1pf(expf(x));
}
__device__ __forceinline__ half8 splat8(_Float16 v) {
  return (half8){v, v, v, v, v, v, v, v};
}
__device__ __forceinline__ half8 fma8(half8 a, half8 b, half8 c) {
  return __builtin_elementwise_fma(a, b, c);
}
__device__ __forceinline__ half8 max8(half8 a, half8 b) {
  return __builtin_elementwise_max(a, b);
}
// async global->LDS, 16B per lane; dest = lds_base + lane*16 (wave-uniform base)
__device__ __forceinline__ void gll16(const void* g, void* l) {
  __builtin_amdgcn_global_load_lds(
      (const __attribute__((address_space(1))) unsigned int*)g,
      (__attribute__((address_space(3))) unsigned int*)l, 16, 0, 0);
}

// ---------------------------------------------------------------------------
// Prep: fused 2-layer MLP -> VT (f16, head-transposed [b][h][d][o]).
__global__ __launch_bounds__(1024) void prep_kernel(
    const float* __restrict__ h_obs, const float* __restrict__ fw1,
    const float* __restrict__ fb1, const float* __restrict__ fw2,
    const float* __restrict__ fb2, _Float16* __restrict__ VT)
{
  __shared__ float s_red[4][4][256];
  __shared__ float s_hid[4][256];
  const int n  = threadIdx.x & 255;
  const int ks = threadIdx.x >> 8;
  const int r0 = blockIdx.x * 4;
  const int k0 = ks * 64;
  float a0 = 0.f, a1 = 0.f, a2 = 0.f, a3 = 0.f;
  #pragma unroll 8
  for (int kk = 0; kk < 64; ++kk) {
    int k = k0 + kk;
    float w = fw1[k * 256 + n];
    a0 = fmaf(h_obs[(r0 + 0) * 256 + k], w, a0);
    a1 = fmaf(h_obs[(r0 + 1) * 256 + k], w, a1);
    a2 = fmaf(h_obs[(r0 + 2) * 256 + k], w, a2);
    a3 = fmaf(h_obs[(r0 + 3) * 256 + k], w, a3);
  }
  s_red[ks][0][n] = a0; s_red[ks][1][n] = a1;
  s_red[ks][2][n] = a2; s_red[ks][3][n] = a3;
  __syncthreads();
  if (ks == 0) {
    float bb = fb1[n];
    #pragma unroll
    for (int r = 0; r < 4; ++r) {
      float v = s_red[0][r][n] + s_red[1][r][n] + s_red[2][r][n] + s_red[3][r][n] + bb;
      s_hid[r][n] = fmaxf(v, 0.f);
    }
  }
  __syncthreads();
  float c0 = 0.f, c1 = 0.f, c2 = 0.f, c3 = 0.f;
  #pragma unroll 8
  for (int kk = 0; kk < 64; ++kk) {
    int k = k0 + kk;
    float w = fw2[k * 256 + n];
    c0 = fmaf(s_hid[0][k], w, c0);
    c1 = fmaf(s_hid[1][k], w, c1);
    c2 = fmaf(s_hid[2][k], w, c2);
    c3 = fmaf(s_hid[3][k], w, c3);
  }
  __syncthreads();
  s_red[ks][0][n] = c0; s_red[ks][1][n] = c1;
  s_red[ks][2][n] = c2; s_red[ks][3][n] = c3;
  __syncthreads();
  if (ks == 0) {
    float bb = fb2[n];
    float vr[4];
    #pragma unroll
    for (int r = 0; r < 4; ++r)
      vr[r] = s_red[0][r][n] + s_red[1][r][n] + s_red[2][r][n] + s_red[3][r][n] + bb;
    // transpose store: thread n owns column (h,d); 4 consecutive o
    const int h  = n >> 5, d = n & 31;
    const int bb_ = r0 >> 9, o0 = r0 & 511;
    half4 pv;
    #pragma unroll
    for (int r = 0; r < 4; ++r) pv[r] = (_Float16)vr[r];
    *(half4*)(VT + ((size_t)((bb_ * 8 + h) * 32 + d)) * 512 + o0) = pv;
  }
}

// ---------------------------------------------------------------------------
// Fused attention (r4 structure, phase-4 removed). QT=2 per block, 512 thr.
// Phase 1: f16 MFMA delta; ao built in-register (rank-3 pos projection).
// Phase 2+3: per-wave (=head), barrier-free; VT staged via global_load_lds
//   into wave-private dead LDS (4-buffer rotation, counted vmcnt).
// Epilogue writes the tiny HV intermediate to global; proj_kernel does
//   out_proj (removing the per-block W stream saved ~25 us — r9 counters).
__global__ __launch_bounds__(512, 4) void attn_fused(
    const _Float16* __restrict__ VT,     // [b][h][d][o] f16
    const float* __restrict__ kw1,       // (9, 256)
    const float* __restrict__ kb1,       // (256)
    const float* __restrict__ kw2,       // (256, 8)
    const float* __restrict__ kb2,       // (8)
    const float* __restrict__ log_sigma, // (8)
    const float* __restrict__ pos_obs,   // (B*NO, 3)
    const float* __restrict__ pos_query, // (B*NQ, 3)
    float* __restrict__ HVg)             // [B*NQ][2][256] f32
{
  __shared__ __align__(16) float s_logits[2][8 * LPAD];   // 33024 B; ph3: per-wave VT stage
  __shared__ __align__(16) _Float16 s_P16[2][8][520];     // 16640 B (P, f16)
  __shared__ half8 s_Bh[512];                             // 8192 B (kw2 frags; ph3: buf0)
  __shared__ __align__(16) float s_pool[256];             // 1024 B (aq f16)
  __shared__ __align__(16) float s_po[3][516];            // 6192 B (pos_obs, SoA)
  __shared__ __align__(16) _Float16 s_co[3][264];         // 1584 B (ao coeff table)

  _Float16* s_aq2 = (_Float16*)s_pool;   // [2][256] f16 (phase 1 only)

  const int t   = threadIdx.x;
  const int bq0 = blockIdx.x * 2;
  const int b   = bq0 >> 9;

  // ---- prologue -----------------------------------------------------------
  float pqx[2], pqy[2], pqz[2];
  #pragma unroll
  for (int q = 0; q < 2; ++q) {
    pqx[q] = pos_query[(bq0 + q) * 3 + 0];
    pqy[q] = pos_query[(bq0 + q) * 3 + 1];
    pqz[q] = pos_query[(bq0 + q) * 3 + 2];
  }
  // aq[q][j] in f16
  {
    const int q = t >> 8, j = t & 255;
    float c0 = kw1[0 * 256 + j] + kw1[6 * 256 + j];
    float c1 = kw1[1 * 256 + j] + kw1[7 * 256 + j];
    float c2 = kw1[2 * 256 + j] + kw1[8 * 256 + j];
    s_aq2[q * 256 + j] = (_Float16)
        fmaf(pqx[q], c0, fmaf(pqy[q], c1, fmaf(pqz[q], c2, kb1[j])));
  }
  // ao coefficient table (rank-3): co[c][j], f16
  if (t < 256) {
    const int j = t;
    s_co[0][j] = (_Float16)(kw1[3 * 256 + j] - kw1[6 * 256 + j]);
    s_co[1][j] = (_Float16)(kw1[4 * 256 + j] - kw1[7 * 256 + j]);
    s_co[2][j] = (_Float16)(kw1[5 * 256 + j] - kw1[8 * 256 + j]);
  }
  // pos_obs SoA + logits prefill (rbf + kb2) for o = t, both q, all h.
  // log(exp(x)+1e-8) ~= max(x, log(1e-8)); clamp region weight < e^-15.
  {
    const int o = t;
    const float* p = pos_obs + (size_t)(b * NO + o) * 3;
    float px = p[0], py = p[1], pz = p[2];
    s_po[0][o] = px; s_po[1][o] = py; s_po[2][o] = pz;
    float d2q[2];
    #pragma unroll
    for (int q = 0; q < 2; ++q) {
      float r0 = pqx[q] - px, r1 = pqy[q] - py, r2 = pqz[q] - pz;
      d2q[q] = r0 * r0 + r1 * r1 + r2 * r2;
    }
    #pragma unroll
    for (int h = 0; h < 8; ++h) {
      float sg  = __expf(log_sigma[h]);
      float inv = 1.0f / (sg * sg + 1e-6f);
      float kbv = kb2[h];
      s_logits[0][h * LPAD + o] = fmaxf(-d2q[0] * inv, -18.420681f) + kbv;
      s_logits[1][h * LPAD + o] = fmaxf(-d2q[1] * inv, -18.420681f) + kbv;
    }
  }
  // B fragments: kw2 as f16
  {
    const int kstep = t >> 6, lane = t & 63;
    const int nh = lane & 15;
    const int kb_ = kstep * 32 + ((lane >> 4) & 3) * 8;
    half8 b8;
    #pragma unroll
    for (int i = 0; i < 8; ++i) {
      float v = (nh < 8) ? kw2[(kb_ + i) * 8 + nh] : 0.f;
      b8[i] = (_Float16)v;
    }
    s_Bh[kstep * 64 + lane] = b8;
  }
  __syncthreads();

  // ---- phase 1: f16 MFMA delta; A = relu(aq + pos.co) all in packed f16 ---
  {
    const int wave = t >> 6, lane = t & 63;
    const int quad = lane >> 4, mrow = lane & 15;
    const int tb   = wave * 4;
    _Float16 pxh[4], pyh[4], pzh[4];
    #pragma unroll
    for (int jt = 0; jt < 4; ++jt) {
      const int o = (tb + jt) * 16 + mrow;
      pxh[jt] = (_Float16)s_po[0][o];
      pyh[jt] = (_Float16)s_po[1][o];
      pzh[jt] = (_Float16)s_po[2][o];
    }
    f32x4 C[2][4];
    #pragma unroll
    for (int q = 0; q < 2; ++q)
      #pragma unroll
      for (int jt = 0; jt < 4; ++jt) C[q][jt] = (f32x4){0.f, 0.f, 0.f, 0.f};

    const half8 z8 = {0, 0, 0, 0, 0, 0, 0, 0};
    #pragma unroll
    for (int kstep = 0; kstep < 8; ++kstep) {
      const int koff = kstep * 32 + quad * 8;
      half8 c0 = *(const half8*)&s_co[0][koff];
      half8 c1 = *(const half8*)&s_co[1][koff];
      half8 c2 = *(const half8*)&s_co[2][koff];
      half8 aq0 = *(const half8*)(s_aq2 + koff);
      half8 aq1 = *(const half8*)(s_aq2 + 256 + koff);
      half8 bh  = s_Bh[kstep * 64 + lane];
      #pragma unroll
      for (int jt = 0; jt < 4; ++jt) {
        half8 ao = fma8(splat8(pxh[jt]), c0,
                   fma8(splat8(pyh[jt]), c1, splat8(pzh[jt]) * c2));
        half8 a0 = max8(aq0 + ao, z8);
        half8 a1 = max8(aq1 + ao, z8);
        C[0][jt] = __builtin_amdgcn_mfma_f32_16x16x32_f16(a0, bh, C[0][jt], 0, 0, 0);
        C[1][jt] = __builtin_amdgcn_mfma_f32_16x16x32_f16(a1, bh, C[1][jt], 0, 0, 0);
      }
    }
    // epilogue: D[n=h=lane&15][m=quad*4+r]; add delta into prefilled logits
    const int hh = lane & 15;
    if (hh < 8) {
      #pragma unroll
      for (int q = 0; q < 2; ++q)
        #pragma unroll
        for (int jt = 0; jt < 4; ++jt) {
          const int ob2 = (tb + jt) * 16 + quad * 4;
          #pragma unroll
          for (int r = 0; r < 4; ++r)
            s_logits[q][hh * LPAD + ob2 + r] += C[q][jt][r];
        }
    }
  }
  __syncthreads();   // logits complete; waves fully independent from here on

  // ---- phase 2+3: per-wave (=head), barrier-free --------------------------
  {
    const int h = t >> 6, lane = t & 63;
    const int kg = lane >> 4, dl = lane & 15;
    // wave-private staging buffers (all dead for everyone else):
    //   buf0 = own s_Bh slot; buf1/buf3 = own q0 logits row; buf2 = own q1 row
    char* stg0 = (char*)s_Bh + h * 1024;
    char* b1   = (char*)&s_logits[0][h * LPAD];
    char* b3   = b1 + 1024;
    char* b2   = (char*)&s_logits[1][h * LPAD];
    const _Float16* vsrc = VT + ((size_t)(b * 8 + h) << 14)
                         + (lane >> 1) * 512 + (lane & 1) * 8;
    gll16(vsrc, stg0);                 // slice 0: hides under softmax

    // softmax, q0/q1 interleaved (2 independent shfl chains -> ILP)
    float invq0, invq1;
    {
      const float* pl0 = &s_logits[0][h * LPAD];
      const float* pl1 = &s_logits[1][h * LPAD];
      float l0[8], l1[8];
      float m0 = -1e30f, m1 = -1e30f;
      #pragma unroll
      for (int k = 0; k < 8; ++k) {
        l0[k] = pl0[k * 64 + lane];
        l1[k] = pl1[k * 64 + lane];
        m0 = fmaxf(m0, l0[k]);
        m1 = fmaxf(m1, l1[k]);
      }
      #pragma unroll
      for (int off = 32; off >= 1; off >>= 1) {
        m0 = fmaxf(m0, __shfl_xor(m0, off, 64));
        m1 = fmaxf(m1, __shfl_xor(m1, off, 64));
      }
      float s0 = 0.f, s1 = 0.f;
      _Float16* pp0 = &s_P16[0][h][0];
      _Float16* pp1 = &s_P16[1][h][0];
      #pragma unroll
      for (int k = 0; k < 8; ++k) {
        float p0 = __expf(l0[k] - m0);
        float p1 = __expf(l1[k] - m1);
        s0 += p0; s1 += p1;
        pp0[k * 64 + lane] = (_Float16)p0;
        pp1[k * 64 + lane] = (_Float16)p1;
      }
      #pragma unroll
      for (int off = 32; off >= 1; off >>= 1) {
        s0 += __shfl_xor(s0, off, 64);
        s1 += __shfl_xor(s1, off, 64);
      }
      invq0 = 1.0f / s0; invq1 = 1.0f / s1;
    }
    // own logits rows now fully read -> become staging buffers
    gll16(vsrc + 16, b1);              // slice 1
    gll16(vsrc + 32, b2);              // slice 2
    gll16(vsrc + 48, b3);              // slice 3

    const char* pE = ((kg & 2) ? b1 : stg0) + dl * 32 + (kg & 1) * 16;
    const char* pO = ((kg & 2) ? b3 : b2)   + dl * 32 + (kg & 1) * 16;
    const _Float16* pB = &s_P16[lane & 1][h][0];
    f32x4 Cm0 = {0.f, 0.f, 0.f, 0.f}, Cm1 = Cm0, Cv0 = Cm0, Cv1 = Cm0;
    #pragma unroll
    for (int kp = 0; kp < 8; ++kp) {
      // even K-step: slices 4kp, 4kp+1 (buf0/buf1)
      asm volatile("s_waitcnt vmcnt(2)" ::: "memory");
      {
        half8 am0 = *(const half8*)(pE);
        half8 am1 = *(const half8*)(pE + 512);       // d + 16
        half8 pb  = *(const half8*)(pB + (2 * kp) * 32 + kg * 8);
        half8 av0 = am0 * am0;
        half8 av1 = am1 * am1;
        __builtin_amdgcn_s_setprio(1);
        Cm0 = __builtin_amdgcn_mfma_f32_16x16x32_f16(am0, pb, Cm0, 0, 0, 0);
        Cm1 = __builtin_amdgcn_mfma_f32_16x16x32_f16(am1, pb, Cm1, 0, 0, 0);
        Cv0 = __builtin_amdgcn_mfma_f32_16x16x32_f16(av0, pb, Cv0, 0, 0, 0);
        Cv1 = __builtin_amdgcn_mfma_f32_16x16x32_f16(av1, pb, Cv1, 0, 0, 0);
        __builtin_amdgcn_s_setprio(0);
      }
      if (kp < 7) {
        asm volatile("s_waitcnt lgkmcnt(0)" ::: "memory");  // reads done; safe to overwrite
        gll16(vsrc + (4 * kp + 4) * 16, stg0);
        gll16(vsrc + (4 * kp + 5) * 16, b1);
      }
      // odd K-step: slices 4kp+2, 4kp+3 (buf2/buf3)
      if (kp < 7) asm volatile("s_waitcnt vmcnt(2)" ::: "memory");
      else        asm volatile("s_waitcnt vmcnt(0)" ::: "memory");
      {
        half8 am0 = *(const half8*)(pO);
        half8 am1 = *(const half8*)(pO + 512);
        half8 pb  = *(const half8*)(pB + (2 * kp + 1) * 32 + kg * 8);
        half8 av0 = am0 * am0;
        half8 av1 = am1 * am1;
        __builtin_amdgcn_s_setprio(1);
        Cm0 = __builtin_amdgcn_mfma_f32_16x16x32_f16(am0, pb, Cm0, 0, 0, 0);
        Cm1 = __builtin_amdgcn_mfma_f32_16x16x32_f16(am1, pb, Cm1, 0, 0, 0);
        Cv0 = __builtin_amdgcn_mfma_f32_16x16x32_f16(av0, pb, Cv0, 0, 0, 0);
        Cv1 = __builtin_amdgcn_mfma_f32_16x16x32_f16(av1, pb, Cv1, 0, 0, 0);
        __builtin_amdgcn_s_setprio(0);
      }
      if (kp < 7) {
        asm volatile("s_waitcnt lgkmcnt(0)" ::: "memory");
        gll16(vsrc + (4 * kp + 6) * 16, b2);
        gll16(vsrc + (4 * kp + 7) * 16, b3);
      }
    }
    // epilogue: C row = kg*4+r (=d_local), col = nq (=q). Normalize + var,
    // write HV intermediate straight to global (no phase 4 in this kernel).
    const int nq = lane & 15;
    if (nq < 2) {
      const float iv = nq ? invq1 : invq0;
      const int dbase = h * 32 + kg * 4;
      f32x4 m0, v0, m1, v1;
      #pragma unroll
      for (int r = 0; r < 4; ++r) {
        float a = Cm0[r] * iv;
        m0[r] = a; v0[r] = fmaxf(Cv0[r] * iv - a * a, 0.f);
        float c = Cm1[r] * iv;
        m1[r] = c; v1[r] = fmaxf(Cv1[r] * iv - c * c, 0.f);
      }
      float* hvq = HVg + (size_t)(bq0 + nq) * 2 * 256;
      *(f32x4*)(hvq + 0 * 256 + dbase)      = m0;   // kind 0: mean path
      *(f32x4*)(hvq + 1 * 256 + dbase)      = v0;   // kind 1: var path
      *(f32x4*)(hvq + 0 * 256 + dbase + 16) = m1;
      *(f32x4*)(hvq + 1 * 256 + dbase + 16) = v1;
    }
  }
}

// ---------------------------------------------------------------------------
// out_proj v2: block = 2 queries x ONE mode, 256 threads (k-split 2 + LDS
// reduce) -> grid 1024 (16 waves/CU): latency hidden by TLP, unlike r9's
// 128-block version (3.9% occupancy, 43 us). W L2 traffic 128 MB ~= 4 us.
__global__ __launch_bounds__(256) void proj_kernel(
    const float* __restrict__ HV,   // [B*NQ][2][256]
    const float* __restrict__ ow, const float* __restrict__ obias,
    const float* __restrict__ vw, const float* __restrict__ vbias,
    float* __restrict__ out)
{
  __shared__ float s_red[2][2][128];   // [ks][q][n]
  const int t  = threadIdx.x;
  const int n  = t & 127, ks = t >> 7;
  const int mode = blockIdx.x & 1;
  const int q0 = (blockIdx.x >> 1) * 2;
  const float* W  = mode ? vw : ow;
  const float* X0 = HV + ((size_t)(q0 + 0) * 2 + mode) * 256;
  const float* X1 = HV + ((size_t)(q0 + 1) * 2 + mode) * 256;
  float a0 = 0.f, a1 = 0.f;
  const int k0 = ks * 128;
  #pragma unroll 8
  for (int k = k0; k < k0 + 128; k += 4) {
    float w0 = W[(k + 0) * 128 + n];
    float w1 = W[(k + 1) * 128 + n];
    float w2 = W[(k + 2) * 128 + n];
    float w3 = W[(k + 3) * 128 + n];
    float4 x0 = *(const float4*)&X0[k];
    float4 x1 = *(const float4*)&X1[k];
    a0 = fmaf(x0.x, w0, a0); a1 = fmaf(x1.x, w0, a1);
    a0 = fmaf(x0.y, w1, a0); a1 = fmaf(x1.y, w1, a1);
    a0 = fmaf(x0.z, w2, a0); a1 = fmaf(x1.z, w2, a1);
    a0 = fmaf(x0.w, w3, a0); a1 = fmaf(x1.w, w3, a1);
  }
  s_red[ks][0][n] = a0;
  s_red[ks][1][n] = a1;
  __syncthreads();
  if (ks == 0) {
    const float bias = mode ? vbias[n] : obias[n];
    #pragma unroll
    for (int qq = 0; qq < 2; ++qq) {
      float v = s_red[0][qq][n] + s_red[1][qq][n] + bias;
      if (mode) v = softplus_f(v);
      out[(size_t)mode * (NB * NQ * OUT_DIM) + (size_t)(q0 + qq) * OUT_DIM + n] = v;
    }
  }
}

// ---------------------------------------------------------------------------
extern "C" void kernel_launch(void* const* d_in, const int* in_sizes, int n_in,
                              void* d_out, int out_size, void* d_ws, size_t ws_size,
                              hipStream_t stream)
{
  const float* h_obs     = (const float*)d_in[0];
  const float* pos_obs   = (const float*)d_in[1];
  const float* pos_query = (const float*)d_in[2];
  const float* fw1       = (const float*)d_in[3];
  const float* fb1       = (const float*)d_in[4];
  const float* fw2       = (const float*)d_in[5];
  const float* fb2       = (const float*)d_in[6];
  const float* log_sigma = (const float*)d_in[7];
  const float* kw1       = (const float*)d_in[8];
  const float* kb1       = (const float*)d_in[9];
  const float* kw2       = (const float*)d_in[10];
  const float* kb2       = (const float*)d_in[11];
  const float* ow        = (const float*)d_in[12];
  const float* ob        = (const float*)d_in[13];
  const float* vw        = (const float*)d_in[14];
  const float* vb        = (const float*)d_in[15];

  float* out = (float*)d_out;
  _Float16* ws = (_Float16*)d_ws;
  _Float16* VT = ws;                       // 262144 f16 = 512 KB
  float*    HV = (float*)(ws + 262144);    // 1024*2*256 f32 = 2 MB

  prep_kernel<<<256, 1024, 0, stream>>>(h_obs, fw1, fb1, fw2, fb2, VT);
  attn_fused<<<NB * NQ / 2, 512, 0, stream>>>(VT, kw1, kb1, kw2, kb2,
                                              log_sigma, pos_obs, pos_query, HV);
  proj_kernel<<<NB * NQ, 256, 0, stream>>>(HV, ow, ob, vw, vb, out);
}

// Round 11
// 130.388 us; speedup vs baseline: 1.0997x; 1.0326x over previous
//
#include <hip/hip_runtime.h>
#include <math.h>

#define NB 2
#define NO 512
#define NQ 512
#define OUT_DIM 128
#define LPAD 516   // logits row pitch (floats): 16B-mult, bank-staggered

typedef __attribute__((ext_vector_type(8))) _Float16 half8;  // 4 VGPR
typedef __attribute__((ext_vector_type(4))) _Float16 half4;  // 2 VGPR
typedef __attribute__((ext_vector_type(4))) float f32x4;     // MFMA acc

__device__ __forceinline__ float softplus_f(float x) {
  return x > 0.0f ? x + log1pf(expf(-x)) : log1pf(expf(x));
}
__device__ __forceinline__ half8 splat8(_Float16 v) {
  return (half8){v, v, v, v, v, v, v, v};
}
__device__ __forceinline__ half8 fma8(half8 a, half8 b, half8 c) {
  return __builtin_elementwise_fma(a, b, c);
}
__device__ __forceinline__ half8 max8(half8 a, half8 b) {
  return __builtin_elementwise_max(a, b);
}
// async global->LDS, 16B per lane; dest = lds_base + lane*16 (wave-uniform base)
__device__ __forceinline__ void gll16(const void* g, void* l) {
  __builtin_amdgcn_global_load_lds(
      (const __attribute__((address_space(1))) unsigned int*)g,
      (__attribute__((address_space(3))) unsigned int*)l, 16, 0, 0);
}

// ---------------------------------------------------------------------------
// Prep: blocks 0..255 fused 2-layer MLP -> VT (f16, head-transposed);
//       blocks 256..287: W2 = [ow | vw] as f16, layout [k][col] (256x256).
__global__ __launch_bounds__(1024) void prep_kernel(
    const float* __restrict__ h_obs, const float* __restrict__ fw1,
    const float* __restrict__ fb1, const float* __restrict__ fw2,
    const float* __restrict__ fb2,
    const float* __restrict__ ow, const float* __restrict__ vw,
    _Float16* __restrict__ VT, _Float16* __restrict__ W2h)
{
  if (blockIdx.x >= 256) {
    const int i  = blockIdx.x - 256;
    const int e0 = (i * 1024 + threadIdx.x) * 2;     // 2 consecutive cols, same k
    const int k = e0 >> 8, col = e0 & 255;
    float v0 = (col < 128) ? ow[k * 128 + col] : vw[k * 128 + col - 128];
    float v1 = (col + 1 < 128) ? ow[k * 128 + col + 1] : vw[k * 128 + col - 127];
    W2h[e0]     = (_Float16)v0;
    W2h[e0 + 1] = (_Float16)v1;
    return;
  }
  __shared__ float s_red[4][4][256];
  __shared__ float s_hid[4][256];
  const int n  = threadIdx.x & 255;
  const int ks = threadIdx.x >> 8;
  const int r0 = blockIdx.x * 4;
  const int k0 = ks * 64;
  float a0 = 0.f, a1 = 0.f, a2 = 0.f, a3 = 0.f;
  #pragma unroll 8
  for (int kk = 0; kk < 64; ++kk) {
    int k = k0 + kk;
    float w = fw1[k * 256 + n];
    a0 = fmaf(h_obs[(r0 + 0) * 256 + k], w, a0);
    a1 = fmaf(h_obs[(r0 + 1) * 256 + k], w, a1);
    a2 = fmaf(h_obs[(r0 + 2) * 256 + k], w, a2);
    a3 = fmaf(h_obs[(r0 + 3) * 256 + k], w, a3);
  }
  s_red[ks][0][n] = a0; s_red[ks][1][n] = a1;
  s_red[ks][2][n] = a2; s_red[ks][3][n] = a3;
  __syncthreads();
  if (ks == 0) {
    float bb = fb1[n];
    #pragma unroll
    for (int r = 0; r < 4; ++r) {
      float v = s_red[0][r][n] + s_red[1][r][n] + s_red[2][r][n] + s_red[3][r][n] + bb;
      s_hid[r][n] = fmaxf(v, 0.f);
    }
  }
  __syncthreads();
  float c0 = 0.f, c1 = 0.f, c2 = 0.f, c3 = 0.f;
  #pragma unroll 8
  for (int kk = 0; kk < 64; ++kk) {
    int k = k0 + kk;
    float w = fw2[k * 256 + n];
    c0 = fmaf(s_hid[0][k], w, c0);
    c1 = fmaf(s_hid[1][k], w, c1);
    c2 = fmaf(s_hid[2][k], w, c2);
    c3 = fmaf(s_hid[3][k], w, c3);
  }
  __syncthreads();
  s_red[ks][0][n] = c0; s_red[ks][1][n] = c1;
  s_red[ks][2][n] = c2; s_red[ks][3][n] = c3;
  __syncthreads();
  if (ks == 0) {
    float bb = fb2[n];
    float vr[4];
    #pragma unroll
    for (int r = 0; r < 4; ++r)
      vr[r] = s_red[0][r][n] + s_red[1][r][n] + s_red[2][r][n] + s_red[3][r][n] + bb;
    // transpose store: thread n owns column (h,d); 4 consecutive o
    const int h  = n >> 5, d = n & 31;
    const int bb_ = r0 >> 9, o0 = r0 & 511;
    half4 pv;
    #pragma unroll
    for (int r = 0; r < 4; ++r) pv[r] = (_Float16)vr[r];
    *(half4*)(VT + ((size_t)((bb_ * 8 + h) * 32 + d)) * 512 + o0) = pv;
  }
}

// ---------------------------------------------------------------------------
// Fused attention + out_proj. QT=2 per block, 512 threads (8 waves).
// Phases 1-3: r4/r10 champion structure (barrier-free per-wave phase 2+3,
//   gll16-staged VT, counted vmcnt). Phase-3 epilogue writes the 4x256 X
//   rows [q0m0,q0m1,q1m0,q1m1] into dead s_po LDS (no global round-trip).
// Phase 4 (new): one output per thread; W2 f16 row-major [k][col] loads —
//   each wave-load = ONE 128B line; 256 independent 2B loads/thread with
//   unroll-4 (32 in flight) -> latency pipelined, no barriers, no W f32
//   stream (the old 25us cost), no separate proj kernel (the 35us cost).
__global__ __launch_bounds__(512, 4) void attn_fused(
    const _Float16* __restrict__ VT,     // [b][h][d][o] f16
    const _Float16* __restrict__ W2h,    // [k][col] f16, col = [ow|vw]
    const float* __restrict__ kw1,       // (9, 256)
    const float* __restrict__ kb1,       // (256)
    const float* __restrict__ kw2,       // (256, 8)
    const float* __restrict__ kb2,       // (8)
    const float* __restrict__ log_sigma, // (8)
    const float* __restrict__ pos_obs,   // (B*NO, 3)
    const float* __restrict__ pos_query, // (B*NQ, 3)
    const float* __restrict__ obias, const float* __restrict__ vbias,
    float* __restrict__ out)
{
  __shared__ __align__(16) float s_logits[2][8 * LPAD];   // 33024 B; ph3: per-wave VT stage
  __shared__ __align__(16) _Float16 s_P16[2][8][520];     // 16640 B (P, f16)
  __shared__ half8 s_Bh[512];                             // 8192 B (kw2 frags; ph3: buf0)
  __shared__ __align__(16) float s_pool[256];             // 1024 B (aq f16)
  __shared__ __align__(16) float s_po[3][516];            // 6192 B (pos SoA; ph4: X rows)
  __shared__ __align__(16) _Float16 s_co[3][264];         // 1584 B (ao coeff table)

  _Float16* s_aq2 = (_Float16*)s_pool;   // [2][256] f16 (phase 1 only)
  float*    s_hvx = (float*)s_po;        // [4 rows][256] X (phase 3 epi -> 4)

  const int t   = threadIdx.x;
  const int bq0 = blockIdx.x * 2;
  const int b   = bq0 >> 9;

  // ---- prologue -----------------------------------------------------------
  float pqx[2], pqy[2], pqz[2];
  #pragma unroll
  for (int q = 0; q < 2; ++q) {
    pqx[q] = pos_query[(bq0 + q) * 3 + 0];
    pqy[q] = pos_query[(bq0 + q) * 3 + 1];
    pqz[q] = pos_query[(bq0 + q) * 3 + 2];
  }
  // aq[q][j] in f16
  {
    const int q = t >> 8, j = t & 255;
    float c0 = kw1[0 * 256 + j] + kw1[6 * 256 + j];
    float c1 = kw1[1 * 256 + j] + kw1[7 * 256 + j];
    float c2 = kw1[2 * 256 + j] + kw1[8 * 256 + j];
    s_aq2[q * 256 + j] = (_Float16)
        fmaf(pqx[q], c0, fmaf(pqy[q], c1, fmaf(pqz[q], c2, kb1[j])));
  }
  // ao coefficient table (rank-3): co[c][j], f16
  if (t < 256) {
    const int j = t;
    s_co[0][j] = (_Float16)(kw1[3 * 256 + j] - kw1[6 * 256 + j]);
    s_co[1][j] = (_Float16)(kw1[4 * 256 + j] - kw1[7 * 256 + j]);
    s_co[2][j] = (_Float16)(kw1[5 * 256 + j] - kw1[8 * 256 + j]);
  }
  // pos_obs SoA + logits prefill (rbf + kb2) for o = t, both q, all h.
  // log(exp(x)+1e-8) ~= max(x, log(1e-8)); clamp region weight < e^-15.
  {
    const int o = t;
    const float* p = pos_obs + (size_t)(b * NO + o) * 3;
    float px = p[0], py = p[1], pz = p[2];
    s_po[0][o] = px; s_po[1][o] = py; s_po[2][o] = pz;
    float d2q[2];
    #pragma unroll
    for (int q = 0; q < 2; ++q) {
      float r0 = pqx[q] - px, r1 = pqy[q] - py, r2 = pqz[q] - pz;
      d2q[q] = r0 * r0 + r1 * r1 + r2 * r2;
    }
    #pragma unroll
    for (int h = 0; h < 8; ++h) {
      float sg  = __expf(log_sigma[h]);
      float inv = 1.0f / (sg * sg + 1e-6f);
      float kbv = kb2[h];
      s_logits[0][h * LPAD + o] = fmaxf(-d2q[0] * inv, -18.420681f) + kbv;
      s_logits[1][h * LPAD + o] = fmaxf(-d2q[1] * inv, -18.420681f) + kbv;
    }
  }
  // B fragments: kw2 as f16
  {
    const int kstep = t >> 6, lane = t & 63;
    const int nh = lane & 15;
    const int kb_ = kstep * 32 + ((lane >> 4) & 3) * 8;
    half8 b8;
    #pragma unroll
    for (int i = 0; i < 8; ++i) {
      float v = (nh < 8) ? kw2[(kb_ + i) * 8 + nh] : 0.f;
      b8[i] = (_Float16)v;
    }
    s_Bh[kstep * 64 + lane] = b8;
  }
  __syncthreads();

  // ---- phase 1: f16 MFMA delta; A = relu(aq + pos.co) all in packed f16 ---
  {
    const int wave = t >> 6, lane = t & 63;
    const int quad = lane >> 4, mrow = lane & 15;
    const int tb   = wave * 4;
    _Float16 pxh[4], pyh[4], pzh[4];
    #pragma unroll
    for (int jt = 0; jt < 4; ++jt) {
      const int o = (tb + jt) * 16 + mrow;
      pxh[jt] = (_Float16)s_po[0][o];
      pyh[jt] = (_Float16)s_po[1][o];
      pzh[jt] = (_Float16)s_po[2][o];
    }
    f32x4 C[2][4];
    #pragma unroll
    for (int q = 0; q < 2; ++q)
      #pragma unroll
      for (int jt = 0; jt < 4; ++jt) C[q][jt] = (f32x4){0.f, 0.f, 0.f, 0.f};

    const half8 z8 = {0, 0, 0, 0, 0, 0, 0, 0};
    #pragma unroll
    for (int kstep = 0; kstep < 8; ++kstep) {
      const int koff = kstep * 32 + quad * 8;
      half8 c0 = *(const half8*)&s_co[0][koff];
      half8 c1 = *(const half8*)&s_co[1][koff];
      half8 c2 = *(const half8*)&s_co[2][koff];
      half8 aq0 = *(const half8*)(s_aq2 + koff);
      half8 aq1 = *(const half8*)(s_aq2 + 256 + koff);
      half8 bh  = s_Bh[kstep * 64 + lane];
      #pragma unroll
      for (int jt = 0; jt < 4; ++jt) {
        half8 ao = fma8(splat8(pxh[jt]), c0,
                   fma8(splat8(pyh[jt]), c1, splat8(pzh[jt]) * c2));
        half8 a0 = max8(aq0 + ao, z8);
        half8 a1 = max8(aq1 + ao, z8);
        C[0][jt] = __builtin_amdgcn_mfma_f32_16x16x32_f16(a0, bh, C[0][jt], 0, 0, 0);
        C[1][jt] = __builtin_amdgcn_mfma_f32_16x16x32_f16(a1, bh, C[1][jt], 0, 0, 0);
      }
    }
    // epilogue: D[n=h=lane&15][m=quad*4+r]; add delta into prefilled logits
    const int hh = lane & 15;
    if (hh < 8) {
      #pragma unroll
      for (int q = 0; q < 2; ++q)
        #pragma unroll
        for (int jt = 0; jt < 4; ++jt) {
          const int ob2 = (tb + jt) * 16 + quad * 4;
          #pragma unroll
          for (int r = 0; r < 4; ++r)
            s_logits[q][hh * LPAD + ob2 + r] += C[q][jt][r];
        }
    }
  }
  __syncthreads();   // logits complete; waves drift through phases 2+3

  // ---- phase 2+3: per-wave (=head), barrier-free --------------------------
  {
    const int h = t >> 6, lane = t & 63;
    const int kg = lane >> 4, dl = lane & 15;
    // wave-private staging buffers (all dead for everyone else):
    //   buf0 = own s_Bh slot; buf1/buf3 = own q0 logits row; buf2 = own q1 row
    char* stg0 = (char*)s_Bh + h * 1024;
    char* b1   = (char*)&s_logits[0][h * LPAD];
    char* b3   = b1 + 1024;
    char* b2   = (char*)&s_logits[1][h * LPAD];
    const _Float16* vsrc = VT + ((size_t)(b * 8 + h) << 14)
                         + (lane >> 1) * 512 + (lane & 1) * 8;
    gll16(vsrc, stg0);                 // slice 0: hides under softmax

    // softmax, q0/q1 interleaved (2 independent shfl chains -> ILP)
    float invq0, invq1;
    {
      const float* pl0 = &s_logits[0][h * LPAD];
      const float* pl1 = &s_logits[1][h * LPAD];
      float l0[8], l1[8];
      float m0 = -1e30f, m1 = -1e30f;
      #pragma unroll
      for (int k = 0; k < 8; ++k) {
        l0[k] = pl0[k * 64 + lane];
        l1[k] = pl1[k * 64 + lane];
        m0 = fmaxf(m0, l0[k]);
        m1 = fmaxf(m1, l1[k]);
      }
      #pragma unroll
      for (int off = 32; off >= 1; off >>= 1) {
        m0 = fmaxf(m0, __shfl_xor(m0, off, 64));
        m1 = fmaxf(m1, __shfl_xor(m1, off, 64));
      }
      float s0 = 0.f, s1 = 0.f;
      _Float16* pp0 = &s_P16[0][h][0];
      _Float16* pp1 = &s_P16[1][h][0];
      #pragma unroll
      for (int k = 0; k < 8; ++k) {
        float p0 = __expf(l0[k] - m0);
        float p1 = __expf(l1[k] - m1);
        s0 += p0; s1 += p1;
        pp0[k * 64 + lane] = (_Float16)p0;
        pp1[k * 64 + lane] = (_Float16)p1;
      }
      #pragma unroll
      for (int off = 32; off >= 1; off >>= 1) {
        s0 += __shfl_xor(s0, off, 64);
        s1 += __shfl_xor(s1, off, 64);
      }
      invq0 = 1.0f / s0; invq1 = 1.0f / s1;
    }
    // own logits rows now fully read -> become staging buffers
    gll16(vsrc + 16, b1);              // slice 1
    gll16(vsrc + 32, b2);              // slice 2
    gll16(vsrc + 48, b3);              // slice 3

    const char* pE = ((kg & 2) ? b1 : stg0) + dl * 32 + (kg & 1) * 16;
    const char* pO = ((kg & 2) ? b3 : b2)   + dl * 32 + (kg & 1) * 16;
    const _Float16* pB = &s_P16[lane & 1][h][0];
    f32x4 Cm0 = {0.f, 0.f, 0.f, 0.f}, Cm1 = Cm0, Cv0 = Cm0, Cv1 = Cm0;
    #pragma unroll
    for (int kp = 0; kp < 8; ++kp) {
      // even K-step: slices 4kp, 4kp+1 (buf0/buf1)
      asm volatile("s_waitcnt vmcnt(2)" ::: "memory");
      {
        half8 am0 = *(const half8*)(pE);
        half8 am1 = *(const half8*)(pE + 512);       // d + 16
        half8 pb  = *(const half8*)(pB + (2 * kp) * 32 + kg * 8);
        half8 av0 = am0 * am0;
        half8 av1 = am1 * am1;
        __builtin_amdgcn_s_setprio(1);
        Cm0 = __builtin_amdgcn_mfma_f32_16x16x32_f16(am0, pb, Cm0, 0, 0, 0);
        Cm1 = __builtin_amdgcn_mfma_f32_16x16x32_f16(am1, pb, Cm1, 0, 0, 0);
        Cv0 = __builtin_amdgcn_mfma_f32_16x16x32_f16(av0, pb, Cv0, 0, 0, 0);
        Cv1 = __builtin_amdgcn_mfma_f32_16x16x32_f16(av1, pb, Cv1, 0, 0, 0);
        __builtin_amdgcn_s_setprio(0);
      }
      if (kp < 7) {
        asm volatile("s_waitcnt lgkmcnt(0)" ::: "memory");  // reads done; safe to overwrite
        gll16(vsrc + (4 * kp + 4) * 16, stg0);
        gll16(vsrc + (4 * kp + 5) * 16, b1);
      }
      // odd K-step: slices 4kp+2, 4kp+3 (buf2/buf3)
      if (kp < 7) asm volatile("s_waitcnt vmcnt(2)" ::: "memory");
      else        asm volatile("s_waitcnt vmcnt(0)" ::: "memory");
      {
        half8 am0 = *(const half8*)(pO);
        half8 am1 = *(const half8*)(pO + 512);
        half8 pb  = *(const half8*)(pB + (2 * kp + 1) * 32 + kg * 8);
        half8 av0 = am0 * am0;
        half8 av1 = am1 * am1;
        __builtin_amdgcn_s_setprio(1);
        Cm0 = __builtin_amdgcn_mfma_f32_16x16x32_f16(am0, pb, Cm0, 0, 0, 0);
        Cm1 = __builtin_amdgcn_mfma_f32_16x16x32_f16(am1, pb, Cm1, 0, 0, 0);
        Cv0 = __builtin_amdgcn_mfma_f32_16x16x32_f16(av0, pb, Cv0, 0, 0, 0);
        Cv1 = __builtin_amdgcn_mfma_f32_16x16x32_f16(av1, pb, Cv1, 0, 0, 0);
        __builtin_amdgcn_s_setprio(0);
      }
      if (kp < 7) {
        asm volatile("s_waitcnt lgkmcnt(0)" ::: "memory");
        gll16(vsrc + (4 * kp + 6) * 16, b2);
        gll16(vsrc + (4 * kp + 7) * 16, b3);
      }
    }
    // epilogue: C row = kg*4+r (=d_local), col = nq (=q). Normalize + var,
    // write X rows [q*2+mode][hd] into dead s_po LDS (stays on-chip).
    const int nq = lane & 15;
    if (nq < 2) {
      const float iv = nq ? invq1 : invq0;
      const int dbase = h * 32 + kg * 4;
      f32x4 m0, v0, m1, v1;
      #pragma unroll
      for (int r = 0; r < 4; ++r) {
        float a = Cm0[r] * iv;
        m0[r] = a; v0[r] = fmaxf(Cv0[r] * iv - a * a, 0.f);
        float c = Cm1[r] * iv;
        m1[r] = c; v1[r] = fmaxf(Cv1[r] * iv - c * c, 0.f);
      }
      *(f32x4*)(s_hvx + (nq * 2 + 0) * 256 + dbase)      = m0;
      *(f32x4*)(s_hvx + (nq * 2 + 1) * 256 + dbase)      = v0;
      *(f32x4*)(s_hvx + (nq * 2 + 0) * 256 + dbase + 16) = m1;
      *(f32x4*)(s_hvx + (nq * 2 + 1) * 256 + dbase + 16) = v1;
    }
  }
  __syncthreads();   // X rows complete

  // ---- phase 4: out_proj from f16 W2, one output per thread ---------------
  {
    const int row = t >> 7, n = t & 127;      // row = q*2 + mode
    const int m = row & 1, qq = row >> 1;
    const float* X = s_hvx + row * 256;
    const _Float16* Wp = W2h + (m * 128 + n); // stride 256 f16 per k
    float acc = 0.f;
    #pragma unroll 4
    for (int k0 = 0; k0 < 256; k0 += 8) {
      float4 xa = *(const float4*)&X[k0];
      float4 xb = *(const float4*)&X[k0 + 4];
      acc = fmaf(xa.x, (float)Wp[(k0 + 0) * 256], acc);
      acc = fmaf(xa.y, (float)Wp[(k0 + 1) * 256], acc);
      acc = fmaf(xa.z, (float)Wp[(k0 + 2) * 256], acc);
      acc = fmaf(xa.w, (float)Wp[(k0 + 3) * 256], acc);
      acc = fmaf(xb.x, (float)Wp[(k0 + 4) * 256], acc);
      acc = fmaf(xb.y, (float)Wp[(k0 + 5) * 256], acc);
      acc = fmaf(xb.z, (float)Wp[(k0 + 6) * 256], acc);
      acc = fmaf(xb.w, (float)Wp[(k0 + 7) * 256], acc);
    }
    float v = acc + (m ? vbias[n] : obias[n]);
    if (m) v = softplus_f(v);
    out[(size_t)m * (NB * NQ * OUT_DIM) + (size_t)(bq0 + qq) * OUT_DIM + n] = v;
  }
}

// ---------------------------------------------------------------------------
extern "C" void kernel_launch(void* const* d_in, const int* in_sizes, int n_in,
                              void* d_out, int out_size, void* d_ws, size_t ws_size,
                              hipStream_t stream)
{
  const float* h_obs     = (const float*)d_in[0];
  const float* pos_obs   = (const float*)d_in[1];
  const float* pos_query = (const float*)d_in[2];
  const float* fw1       = (const float*)d_in[3];
  const float* fb1       = (const float*)d_in[4];
  const float* fw2       = (const float*)d_in[5];
  const float* fb2       = (const float*)d_in[6];
  const float* log_sigma = (const float*)d_in[7];
  const float* kw1       = (const float*)d_in[8];
  const float* kb1       = (const float*)d_in[9];
  const float* kw2       = (const float*)d_in[10];
  const float* kb2       = (const float*)d_in[11];
  const float* ow        = (const float*)d_in[12];
  const float* ob        = (const float*)d_in[13];
  const float* vw        = (const float*)d_in[14];
  const float* vb        = (const float*)d_in[15];

  float* out = (float*)d_out;
  _Float16* ws = (_Float16*)d_ws;
  _Float16* VT  = ws;                  // 262144 f16 = 512 KB
  _Float16* W2h = ws + 262144;         // 65536 f16 = 128 KB

  prep_kernel<<<288, 1024, 0, stream>>>(h_obs, fw1, fb1, fw2, fb2, ow, vw,
                                        VT, W2h);
  attn_fused<<<NB * NQ / 2, 512, 0, stream>>>(VT, W2h, kw1, kb1, kw2, kb2,
                                              log_sigma, pos_obs, pos_query,
                                              ob, vb, out);
}

// Round 12
// 126.988 us; speedup vs baseline: 1.1291x; 1.0268x over previous
//
#include <hip/hip_runtime.h>
#include <math.h>

#define NB 2
#define NO 512
#define NQ 512
#define OUT_DIM 128
#define LPAD 516   // logits row pitch (floats): 16B-mult, bank-staggered

typedef __attribute__((ext_vector_type(8))) _Float16 half8;  // 4 VGPR
typedef __attribute__((ext_vector_type(4))) _Float16 half4;  // 2 VGPR
typedef __attribute__((ext_vector_type(2))) _Float16 h2v;    // 2 f16
typedef __attribute__((ext_vector_type(4))) float f32x4;     // MFMA acc

__device__ __forceinline__ float softplus_f(float x) {
  return x > 0.0f ? x + log1pf(expf(-x)) : log1pf(expf(x));
}
__device__ __forceinline__ half8 splat8(_Float16 v) {
  return (half8){v, v, v, v, v, v, v, v};
}
__device__ __forceinline__ half8 fma8(half8 a, half8 b, half8 c) {
  return __builtin_elementwise_fma(a, b, c);
}
__device__ __forceinline__ half8 max8(half8 a, half8 b) {
  return __builtin_elementwise_max(a, b);
}
// async global->LDS, 16B per lane; dest = lds_base + lane*16 (wave-uniform base)
__device__ __forceinline__ void gll16(const void* g, void* l) {
  __builtin_amdgcn_global_load_lds(
      (const __attribute__((address_space(1))) unsigned int*)g,
      (__attribute__((address_space(3))) unsigned int*)l, 16, 0, 0);
}

// ---------------------------------------------------------------------------
// Prep: blocks 0..255 fused 2-layer MLP -> VT (f16, head-transposed);
//       blocks 256..287: W2 = [ow | vw] as f16, layout [k][col] (256x256).
__global__ __launch_bounds__(1024) void prep_kernel(
    const float* __restrict__ h_obs, const float* __restrict__ fw1,
    const float* __restrict__ fb1, const float* __restrict__ fw2,
    const float* __restrict__ fb2,
    const float* __restrict__ ow, const float* __restrict__ vw,
    _Float16* __restrict__ VT, _Float16* __restrict__ W2h)
{
  if (blockIdx.x >= 256) {
    const int i  = blockIdx.x - 256;
    const int e0 = (i * 1024 + threadIdx.x) * 2;     // 2 consecutive cols, same k
    const int k = e0 >> 8, col = e0 & 255;
    float v0 = (col < 128) ? ow[k * 128 + col] : vw[k * 128 + col - 128];
    float v1 = (col + 1 < 128) ? ow[k * 128 + col + 1] : vw[k * 128 + col - 127];
    W2h[e0]     = (_Float16)v0;
    W2h[e0 + 1] = (_Float16)v1;
    return;
  }
  __shared__ float s_red[4][4][256];
  __shared__ float s_hid[4][256];
  const int n  = threadIdx.x & 255;
  const int ks = threadIdx.x >> 8;
  const int r0 = blockIdx.x * 4;
  const int k0 = ks * 64;
  float a0 = 0.f, a1 = 0.f, a2 = 0.f, a3 = 0.f;
  #pragma unroll 8
  for (int kk = 0; kk < 64; ++kk) {
    int k = k0 + kk;
    float w = fw1[k * 256 + n];
    a0 = fmaf(h_obs[(r0 + 0) * 256 + k], w, a0);
    a1 = fmaf(h_obs[(r0 + 1) * 256 + k], w, a1);
    a2 = fmaf(h_obs[(r0 + 2) * 256 + k], w, a2);
    a3 = fmaf(h_obs[(r0 + 3) * 256 + k], w, a3);
  }
  s_red[ks][0][n] = a0; s_red[ks][1][n] = a1;
  s_red[ks][2][n] = a2; s_red[ks][3][n] = a3;
  __syncthreads();
  if (ks == 0) {
    float bb = fb1[n];
    #pragma unroll
    for (int r = 0; r < 4; ++r) {
      float v = s_red[0][r][n] + s_red[1][r][n] + s_red[2][r][n] + s_red[3][r][n] + bb;
      s_hid[r][n] = fmaxf(v, 0.f);
    }
  }
  __syncthreads();
  float c0 = 0.f, c1 = 0.f, c2 = 0.f, c3 = 0.f;
  #pragma unroll 8
  for (int kk = 0; kk < 64; ++kk) {
    int k = k0 + kk;
    float w = fw2[k * 256 + n];
    c0 = fmaf(s_hid[0][k], w, c0);
    c1 = fmaf(s_hid[1][k], w, c1);
    c2 = fmaf(s_hid[2][k], w, c2);
    c3 = fmaf(s_hid[3][k], w, c3);
  }
  __syncthreads();
  s_red[ks][0][n] = c0; s_red[ks][1][n] = c1;
  s_red[ks][2][n] = c2; s_red[ks][3][n] = c3;
  __syncthreads();
  if (ks == 0) {
    float bb = fb2[n];
    float vr[4];
    #pragma unroll
    for (int r = 0; r < 4; ++r)
      vr[r] = s_red[0][r][n] + s_red[1][r][n] + s_red[2][r][n] + s_red[3][r][n] + bb;
    // transpose store: thread n owns column (h,d); 4 consecutive o
    const int h  = n >> 5, d = n & 31;
    const int bb_ = r0 >> 9, o0 = r0 & 511;
    half4 pv;
    #pragma unroll
    for (int r = 0; r < 4; ++r) pv[r] = (_Float16)vr[r];
    *(half4*)(VT + ((size_t)((bb_ * 8 + h) * 32 + d)) * 512 + o0) = pv;
  }
}

// ---------------------------------------------------------------------------
// Fused attention + out_proj. QT=2 per block, 512 threads (8 waves).
// Phases 1-3: r4 champion structure. Phase 4: W2 streamed via
// global_load_lds (DMA path) — per-lane W loads are the proven ~10x-slow
// path (r4/r9/r10/r11 all ~25-40us); gll streams (VT) run at full rate.
// Per wave: own 32-k slice of W2 in 16x1KB chunks through 5 wave-private
// dead buffers, counted vmcnt(4); partials to dead logits[1]; reduce.
__global__ __launch_bounds__(512, 4) void attn_fused(
    const _Float16* __restrict__ VT,     // [b][h][d][o] f16
    const _Float16* __restrict__ W2h,    // [k][col] f16, col = [ow|vw]
    const float* __restrict__ kw1,       // (9, 256)
    const float* __restrict__ kb1,       // (256)
    const float* __restrict__ kw2,       // (256, 8)
    const float* __restrict__ kb2,       // (8)
    const float* __restrict__ log_sigma, // (8)
    const float* __restrict__ pos_obs,   // (B*NO, 3)
    const float* __restrict__ pos_query, // (B*NQ, 3)
    const float* __restrict__ obias, const float* __restrict__ vbias,
    float* __restrict__ out)
{
  __shared__ __align__(16) float s_logits[2][8 * LPAD];   // 33024 B; ph3 stage; ph4 stage+partials
  __shared__ __align__(16) _Float16 s_P16[8][2][520];     // 16640 B (P; ph4: stage bufs B,C)
  __shared__ half8 s_Bh[512];                             // 8192 B (kw2 frags; ph3/4: buf)
  __shared__ __align__(16) float s_pool[256];             // 1024 B (aq f16)
  __shared__ __align__(16) float s_po[3][516];            // 6192 B (pos SoA; ph4: X rows)
  __shared__ __align__(16) _Float16 s_co[3][264];         // 1584 B (ao coeff table)

  _Float16* s_aq2 = (_Float16*)s_pool;   // [2][256] f16 (phase 1 only)
  float*    s_hvx = (float*)s_po;        // [4 rows][256] X (phase 3 epi -> 4)

  const int t   = threadIdx.x;
  const int bq0 = blockIdx.x * 2;
  const int b   = bq0 >> 9;

  // ---- prologue -----------------------------------------------------------
  float pqx[2], pqy[2], pqz[2];
  #pragma unroll
  for (int q = 0; q < 2; ++q) {
    pqx[q] = pos_query[(bq0 + q) * 3 + 0];
    pqy[q] = pos_query[(bq0 + q) * 3 + 1];
    pqz[q] = pos_query[(bq0 + q) * 3 + 2];
  }
  // aq[q][j] in f16
  {
    const int q = t >> 8, j = t & 255;
    float c0 = kw1[0 * 256 + j] + kw1[6 * 256 + j];
    float c1 = kw1[1 * 256 + j] + kw1[7 * 256 + j];
    float c2 = kw1[2 * 256 + j] + kw1[8 * 256 + j];
    s_aq2[q * 256 + j] = (_Float16)
        fmaf(pqx[q], c0, fmaf(pqy[q], c1, fmaf(pqz[q], c2, kb1[j])));
  }
  // ao coefficient table (rank-3): co[c][j], f16
  if (t < 256) {
    const int j = t;
    s_co[0][j] = (_Float16)(kw1[3 * 256 + j] - kw1[6 * 256 + j]);
    s_co[1][j] = (_Float16)(kw1[4 * 256 + j] - kw1[7 * 256 + j]);
    s_co[2][j] = (_Float16)(kw1[5 * 256 + j] - kw1[8 * 256 + j]);
  }
  // pos_obs SoA + logits prefill (rbf + kb2) for o = t, both q, all h.
  // log(exp(x)+1e-8) ~= max(x, log(1e-8)); clamp region weight < e^-15.
  {
    const int o = t;
    const float* p = pos_obs + (size_t)(b * NO + o) * 3;
    float px = p[0], py = p[1], pz = p[2];
    s_po[0][o] = px; s_po[1][o] = py; s_po[2][o] = pz;
    float d2q[2];
    #pragma unroll
    for (int q = 0; q < 2; ++q) {
      float r0 = pqx[q] - px, r1 = pqy[q] - py, r2 = pqz[q] - pz;
      d2q[q] = r0 * r0 + r1 * r1 + r2 * r2;
    }
    #pragma unroll
    for (int h = 0; h < 8; ++h) {
      float sg  = __expf(log_sigma[h]);
      float inv = 1.0f / (sg * sg + 1e-6f);
      float kbv = kb2[h];
      s_logits[0][h * LPAD + o] = fmaxf(-d2q[0] * inv, -18.420681f) + kbv;
      s_logits[1][h * LPAD + o] = fmaxf(-d2q[1] * inv, -18.420681f) + kbv;
    }
  }
  // B fragments: kw2 as f16
  {
    const int kstep = t >> 6, lane = t & 63;
    const int nh = lane & 15;
    const int kb_ = kstep * 32 + ((lane >> 4) & 3) * 8;
    half8 b8;
    #pragma unroll
    for (int i = 0; i < 8; ++i) {
      float v = (nh < 8) ? kw2[(kb_ + i) * 8 + nh] : 0.f;
      b8[i] = (_Float16)v;
    }
    s_Bh[kstep * 64 + lane] = b8;
  }
  __syncthreads();

  // ---- phase 1: f16 MFMA delta; A = relu(aq + pos.co) all in packed f16 ---
  {
    const int wave = t >> 6, lane = t & 63;
    const int quad = lane >> 4, mrow = lane & 15;
    const int tb   = wave * 4;
    _Float16 pxh[4], pyh[4], pzh[4];
    #pragma unroll
    for (int jt = 0; jt < 4; ++jt) {
      const int o = (tb + jt) * 16 + mrow;
      pxh[jt] = (_Float16)s_po[0][o];
      pyh[jt] = (_Float16)s_po[1][o];
      pzh[jt] = (_Float16)s_po[2][o];
    }
    f32x4 C[2][4];
    #pragma unroll
    for (int q = 0; q < 2; ++q)
      #pragma unroll
      for (int jt = 0; jt < 4; ++jt) C[q][jt] = (f32x4){0.f, 0.f, 0.f, 0.f};

    const half8 z8 = {0, 0, 0, 0, 0, 0, 0, 0};
    #pragma unroll
    for (int kstep = 0; kstep < 8; ++kstep) {
      const int koff = kstep * 32 + quad * 8;
      half8 c0 = *(const half8*)&s_co[0][koff];
      half8 c1 = *(const half8*)&s_co[1][koff];
      half8 c2 = *(const half8*)&s_co[2][koff];
      half8 aq0 = *(const half8*)(s_aq2 + koff);
      half8 aq1 = *(const half8*)(s_aq2 + 256 + koff);
      half8 bh  = s_Bh[kstep * 64 + lane];
      #pragma unroll
      for (int jt = 0; jt < 4; ++jt) {
        half8 ao = fma8(splat8(pxh[jt]), c0,
                   fma8(splat8(pyh[jt]), c1, splat8(pzh[jt]) * c2));
        half8 a0 = max8(aq0 + ao, z8);
        half8 a1 = max8(aq1 + ao, z8);
        C[0][jt] = __builtin_amdgcn_mfma_f32_16x16x32_f16(a0, bh, C[0][jt], 0, 0, 0);
        C[1][jt] = __builtin_amdgcn_mfma_f32_16x16x32_f16(a1, bh, C[1][jt], 0, 0, 0);
      }
    }
    // epilogue: D[n=h=lane&15][m=quad*4+r]; add delta into prefilled logits
    const int hh = lane & 15;
    if (hh < 8) {
      #pragma unroll
      for (int q = 0; q < 2; ++q)
        #pragma unroll
        for (int jt = 0; jt < 4; ++jt) {
          const int ob2 = (tb + jt) * 16 + quad * 4;
          #pragma unroll
          for (int r = 0; r < 4; ++r)
            s_logits[q][hh * LPAD + ob2 + r] += C[q][jt][r];
        }
    }
  }
  __syncthreads();   // logits complete; waves drift through phases 2+3

  // ---- phase 2+3: per-wave (=head), barrier-free --------------------------
  {
    const int h = t >> 6, lane = t & 63;
    const int kg = lane >> 4, dl = lane & 15;
    // wave-private staging buffers (all dead for everyone else):
    char* stg0 = (char*)s_Bh + h * 1024;
    char* b1   = (char*)&s_logits[0][h * LPAD];
    char* b3   = b1 + 1024;
    char* b2   = (char*)&s_logits[1][h * LPAD];
    const _Float16* vsrc = VT + ((size_t)(b * 8 + h) << 14)
                         + (lane >> 1) * 512 + (lane & 1) * 8;
    gll16(vsrc, stg0);                 // slice 0: hides under softmax

    // softmax, q0/q1 interleaved (2 independent shfl chains -> ILP)
    float invq0, invq1;
    {
      const float* pl0 = &s_logits[0][h * LPAD];
      const float* pl1 = &s_logits[1][h * LPAD];
      float l0[8], l1[8];
      float m0 = -1e30f, m1 = -1e30f;
      #pragma unroll
      for (int k = 0; k < 8; ++k) {
        l0[k] = pl0[k * 64 + lane];
        l1[k] = pl1[k * 64 + lane];
        m0 = fmaxf(m0, l0[k]);
        m1 = fmaxf(m1, l1[k]);
      }
      #pragma unroll
      for (int off = 32; off >= 1; off >>= 1) {
        m0 = fmaxf(m0, __shfl_xor(m0, off, 64));
        m1 = fmaxf(m1, __shfl_xor(m1, off, 64));
      }
      float s0 = 0.f, s1 = 0.f;
      _Float16* pp0 = &s_P16[h][0][0];
      _Float16* pp1 = &s_P16[h][1][0];
      #pragma unroll
      for (int k = 0; k < 8; ++k) {
        float p0 = __expf(l0[k] - m0);
        float p1 = __expf(l1[k] - m1);
        s0 += p0; s1 += p1;
        pp0[k * 64 + lane] = (_Float16)p0;
        pp1[k * 64 + lane] = (_Float16)p1;
      }
      #pragma unroll
      for (int off = 32; off >= 1; off >>= 1) {
        s0 += __shfl_xor(s0, off, 64);
        s1 += __shfl_xor(s1, off, 64);
      }
      invq0 = 1.0f / s0; invq1 = 1.0f / s1;
    }
    // own logits rows now fully read -> become staging buffers
    gll16(vsrc + 16, b1);              // slice 1
    gll16(vsrc + 32, b2);              // slice 2
    gll16(vsrc + 48, b3);              // slice 3

    const char* pE = ((kg & 2) ? b1 : stg0) + dl * 32 + (kg & 1) * 16;
    const char* pO = ((kg & 2) ? b3 : b2)   + dl * 32 + (kg & 1) * 16;
    const _Float16* pB = &s_P16[h][lane & 1][0];
    f32x4 Cm0 = {0.f, 0.f, 0.f, 0.f}, Cm1 = Cm0, Cv0 = Cm0, Cv1 = Cm0;
    #pragma unroll
    for (int kp = 0; kp < 8; ++kp) {
      // even K-step: slices 4kp, 4kp+1 (buf0/buf1)
      asm volatile("s_waitcnt vmcnt(2)" ::: "memory");
      {
        half8 am0 = *(const half8*)(pE);
        half8 am1 = *(const half8*)(pE + 512);       // d + 16
        half8 pb  = *(const half8*)(pB + (2 * kp) * 32 + kg * 8);
        half8 av0 = am0 * am0;
        half8 av1 = am1 * am1;
        __builtin_amdgcn_s_setprio(1);
        Cm0 = __builtin_amdgcn_mfma_f32_16x16x32_f16(am0, pb, Cm0, 0, 0, 0);
        Cm1 = __builtin_amdgcn_mfma_f32_16x16x32_f16(am1, pb, Cm1, 0, 0, 0);
        Cv0 = __builtin_amdgcn_mfma_f32_16x16x32_f16(av0, pb, Cv0, 0, 0, 0);
        Cv1 = __builtin_amdgcn_mfma_f32_16x16x32_f16(av1, pb, Cv1, 0, 0, 0);
        __builtin_amdgcn_s_setprio(0);
      }
      if (kp < 7) {
        asm volatile("s_waitcnt lgkmcnt(0)" ::: "memory");  // reads done; safe to overwrite
        gll16(vsrc + (4 * kp + 4) * 16, stg0);
        gll16(vsrc + (4 * kp + 5) * 16, b1);
      }
      // odd K-step: slices 4kp+2, 4kp+3 (buf2/buf3)
      if (kp < 7) asm volatile("s_waitcnt vmcnt(2)" ::: "memory");
      else        asm volatile("s_waitcnt vmcnt(0)" ::: "memory");
      {
        half8 am0 = *(const half8*)(pO);
        half8 am1 = *(const half8*)(pO + 512);
        half8 pb  = *(const half8*)(pB + (2 * kp + 1) * 32 + kg * 8);
        half8 av0 = am0 * am0;
        half8 av1 = am1 * am1;
        __builtin_amdgcn_s_setprio(1);
        Cm0 = __builtin_amdgcn_mfma_f32_16x16x32_f16(am0, pb, Cm0, 0, 0, 0);
        Cm1 = __builtin_amdgcn_mfma_f32_16x16x32_f16(am1, pb, Cm1, 0, 0, 0);
        Cv0 = __builtin_amdgcn_mfma_f32_16x16x32_f16(av0, pb, Cv0, 0, 0, 0);
        Cv1 = __builtin_amdgcn_mfma_f32_16x16x32_f16(av1, pb, Cv1, 0, 0, 0);
        __builtin_amdgcn_s_setprio(0);
      }
      if (kp < 7) {
        asm volatile("s_waitcnt lgkmcnt(0)" ::: "memory");
        gll16(vsrc + (4 * kp + 6) * 16, b2);
        gll16(vsrc + (4 * kp + 7) * 16, b3);
      }
    }
    // epilogue: C row = kg*4+r (=d_local), col = nq (=q). Normalize + var,
    // write X rows [q*2+mode][hd] into dead s_po LDS (stays on-chip).
    const int nq = lane & 15;
    if (nq < 2) {
      const float iv = nq ? invq1 : invq0;
      const int dbase = h * 32 + kg * 4;
      f32x4 m0, v0, m1, v1;
      #pragma unroll
      for (int r = 0; r < 4; ++r) {
        float a = Cm0[r] * iv;
        m0[r] = a; v0[r] = fmaxf(Cv0[r] * iv - a * a, 0.f);
        float c = Cm1[r] * iv;
        m1[r] = c; v1[r] = fmaxf(Cv1[r] * iv - c * c, 0.f);
      }
      *(f32x4*)(s_hvx + (nq * 2 + 0) * 256 + dbase)      = m0;
      *(f32x4*)(s_hvx + (nq * 2 + 1) * 256 + dbase)      = v0;
      *(f32x4*)(s_hvx + (nq * 2 + 0) * 256 + dbase + 16) = m1;
      *(f32x4*)(s_hvx + (nq * 2 + 1) * 256 + dbase + 16) = v1;
    }
    // phase-4 prologue: stage first 5 W2 chunks (wave h owns k in [32h,32h+32))
    // into wave-private dead LDS. All phase-3 reads of these regions are done.
    asm volatile("s_waitcnt lgkmcnt(0)" ::: "memory");
    const _Float16* wsrc = W2h + h * 32 * 256 + lane * 8;
    char* f4B = (char*)&s_P16[h][0][0];
    gll16(wsrc + 0 * 512, stg0);       // buf A = own s_Bh slot
    gll16(wsrc + 1 * 512, f4B);        // buf B = own P slot, first KB
    gll16(wsrc + 2 * 512, f4B + 1024); // buf C = own P slot, second KB
    gll16(wsrc + 3 * 512, b1);         // buf D = own logits[0] row, first KB
    gll16(wsrc + 4 * 512, b3);         // buf E = own logits[0] row, second KB
  }
  __syncthreads();   // X complete; all waves past phase 3

  // ---- phase 4: out_proj, W2 via gll DMA, per-wave k-split ----------------
  {
    const int h = t >> 6, l = t & 63;
    char* f4A = (char*)s_Bh + h * 1024;
    char* f4B = (char*)&s_P16[h][0][0];
    char* f4C = f4B + 1024;
    char* f4D = (char*)&s_logits[0][h * LPAD];
    char* f4E = f4D + 1024;
    const _Float16* wsrc = W2h + h * 32 * 256 + l * 8;
    const float* Xr = s_hvx;
    float a00 = 0.f, a01 = 0.f, a10 = 0.f, a11 = 0.f;
    float a20 = 0.f, a21 = 0.f, a30 = 0.f, a31 = 0.f;

#define P4STEP(c, BUF, WN, REFILL)                                          \
    { asm volatile("s_waitcnt vmcnt(" WN ")" ::: "memory");                 \
      const char* bp4 = (BUF);                                              \
      _Pragma("unroll")                                                     \
      for (int kr = 0; kr < 2; ++kr) {                                      \
        const int k = h * 32 + (c) * 2 + kr;                                \
        unsigned uw0 = *(const unsigned*)(bp4 + kr * 512 + l * 4);          \
        unsigned uw1 = *(const unsigned*)(bp4 + kr * 512 + 256 + l * 4);    \
        h2v p0 = __builtin_bit_cast(h2v, uw0);                              \
        h2v p1 = __builtin_bit_cast(h2v, uw1);                              \
        float w0a = (float)p0.x, w0b = (float)p0.y;                         \
        float w1a = (float)p1.x, w1b = (float)p1.y;                         \
        float x0 = Xr[k], x1 = Xr[256 + k];                                 \
        float x2 = Xr[512 + k], x3 = Xr[768 + k];                           \
        a00 = fmaf(x0, w0a, a00); a01 = fmaf(x0, w0b, a01);                 \
        a20 = fmaf(x2, w0a, a20); a21 = fmaf(x2, w0b, a21);                 \
        a10 = fmaf(x1, w1a, a10); a11 = fmaf(x1, w1b, a11);                 \
        a30 = fmaf(x3, w1a, a30); a31 = fmaf(x3, w1b, a31);                 \
      }                                                                     \
      REFILL }
#define RFL(c, BUF) \
      asm volatile("s_waitcnt lgkmcnt(0)" ::: "memory"); \
      gll16(wsrc + (c) * 512, BUF);

    P4STEP( 0, f4A, "4", RFL( 5, f4A))
    P4STEP( 1, f4B, "4", RFL( 6, f4B))
    P4STEP( 2, f4C, "4", RFL( 7, f4C))
    P4STEP( 3, f4D, "4", RFL( 8, f4D))
    P4STEP( 4, f4E, "4", RFL( 9, f4E))
    P4STEP( 5, f4A, "4", RFL(10, f4A))
    P4STEP( 6, f4B, "4", RFL(11, f4B))
    P4STEP( 7, f4C, "4", RFL(12, f4C))
    P4STEP( 8, f4D, "4", RFL(13, f4D))
    P4STEP( 9, f4E, "4", RFL(14, f4E))
    P4STEP(10, f4A, "4", RFL(15, f4A))
    P4STEP(11, f4B, "4", )
    P4STEP(12, f4C, "3", )
    P4STEP(13, f4D, "2", )
    P4STEP(14, f4E, "1", )
    P4STEP(15, f4A, "0", )
#undef RFL
#undef P4STEP

    // per-wave partials -> dead logits[1] region: [wave][4 rows][129]
    float* pw = (float*)((char*)s_logits + 8 * LPAD * 4 + h * 2064);
    pw[0 * 129 + 2 * l] = a00; pw[0 * 129 + 2 * l + 1] = a01;
    pw[1 * 129 + 2 * l] = a10; pw[1 * 129 + 2 * l + 1] = a11;
    pw[2 * 129 + 2 * l] = a20; pw[2 * 129 + 2 * l + 1] = a21;
    pw[3 * 129 + 2 * l] = a30; pw[3 * 129 + 2 * l + 1] = a31;
  }
  __syncthreads();

  // ---- reduce: one output per thread --------------------------------------
  {
    const int row = t >> 7, n = t & 127;      // row = q*2 + mode
    const int m = row & 1, qq = row >> 1;
    float acc = 0.f;
    #pragma unroll
    for (int w = 0; w < 8; ++w)
      acc += ((const float*)((char*)s_logits + 8 * LPAD * 4 + w * 2064))[row * 129 + n];
    float v = acc + (m ? vbias[n] : obias[n]);
    if (m) v = softplus_f(v);
    out[(size_t)m * (NB * NQ * OUT_DIM) + (size_t)(bq0 + qq) * OUT_DIM + n] = v;
  }
}

// ---------------------------------------------------------------------------
extern "C" void kernel_launch(void* const* d_in, const int* in_sizes, int n_in,
                              void* d_out, int out_size, void* d_ws, size_t ws_size,
                              hipStream_t stream)
{
  const float* h_obs     = (const float*)d_in[0];
  const float* pos_obs   = (const float*)d_in[1];
  const float* pos_query = (const float*)d_in[2];
  const float* fw1       = (const float*)d_in[3];
  const float* fb1       = (const float*)d_in[4];
  const float* fw2       = (const float*)d_in[5];
  const float* fb2       = (const float*)d_in[6];
  const float* log_sigma = (const float*)d_in[7];
  const float* kw1       = (const float*)d_in[8];
  const float* kb1       = (const float*)d_in[9];
  const float* kw2       = (const float*)d_in[10];
  const float* kb2       = (const float*)d_in[11];
  const float* ow        = (const float*)d_in[12];
  const float* ob        = (const float*)d_in[13];
  const float* vw        = (const float*)d_in[14];
  const float* vb        = (const float*)d_in[15];

  float* out = (float*)d_out;
  _Float16* ws = (_Float16*)d_ws;
  _Float16* VT  = ws;                  // 262144 f16 = 512 KB
  _Float16* W2h = ws + 262144;         // 65536 f16 = 128 KB

  prep_kernel<<<288, 1024, 0, stream>>>(h_obs, fw1, fb1, fw2, fb2, ow, vw,
                                        VT, W2h);
  attn_fused<<<NB * NQ / 2, 512, 0, stream>>>(VT, W2h, kw1, kb1, kw2, kb2,
                                              log_sigma, pos_obs, pos_query,
                                              ob, vb, out);
}